// Round 4
// baseline (475.933 us; speedup 1.0000x reference)
//
#include <hip/hip_runtime.h>
#include <stdint.h>

// CausalMultiHeadAttention — round 6 (third resubmit; rounds 1-3 were infra
// GPUAcquisitionTimeouts, no counters produced).
//  - x pre-converted fp32->bf16 once (into the O slot: xb dead before attn
//    writes O there). All 4 GEMMs stage A via global_load_lds width=16
//    (async, no VGPR round-trip, no per-block reconvert). W stays pk8.
//  - QKV merged into ONE launch (grid 24x64 = 1536 blocks), V keeps its
//    transposed epilogue via a wave-uniform branch on the mfma operand order.
//  - GEMM occupancy cap relaxed to 3 blocks/CU (launch_bounds(256,3)).
//  - attn: balanced pairing — each block handles query-blocks (i, 31-i) so
//    every block does exactly 33 K-tile iterations (was 1..32 -> occupancy
//    decayed to 26%). Grid 16x64 = 1024 uniform blocks, 4/CU steady.
// ws: Q | K | Vt (fp16) | {xb then O} (bf16) = 67.1 MB (proven size).

#define D_MODEL 1024
#define NHEAD   16
#define DK      64
#define BATCH   4
#define SEQ     2048
#define MTOT    (BATCH*SEQ)   // 8192

typedef unsigned short u16;
typedef unsigned int   u32;
typedef __bf16    bf16x8  __attribute__((ext_vector_type(8)));
typedef float     floatx4 __attribute__((ext_vector_type(4)));
typedef __fp16    fp16x2  __attribute__((ext_vector_type(2)));
typedef _Float16  half4_t __attribute__((ext_vector_type(4)));
typedef _Float16  half8_t __attribute__((ext_vector_type(8)));

// round-to-nearest-even f32 -> bf16 (epilogue only)
__device__ __forceinline__ u16 f2bf(float f){
  union { float f; u32 u; } c; c.f = f;
  u32 x = c.u;
  x += 0x7fffu + ((x >> 16) & 1u);
  return (u16)(x >> 16);
}
// f32 pair -> packed fp16 bits (RTZ, hardware packed cvt)
__device__ __forceinline__ u32 pkh(float a, float b){
  union { fp16x2 h; u32 u; } c; c.h = __builtin_amdgcn_cvt_pkrtz(a, b); return c.u;
}
// 8 fp32 -> 8 bf16 by truncation: one v_perm per pair
__device__ __forceinline__ uint4 pk8(const float* __restrict__ p){
  uint4 a = *(const uint4*)p;
  uint4 b = *(const uint4*)(p + 4);
  uint4 r;
  r.x = __builtin_amdgcn_perm(a.y, a.x, 0x07060302);
  r.y = __builtin_amdgcn_perm(a.w, a.z, 0x07060302);
  r.z = __builtin_amdgcn_perm(b.y, b.x, 0x07060302);
  r.w = __builtin_amdgcn_perm(b.w, b.z, 0x07060302);
  return r;
}
// async global->LDS, 16B per lane. LDS dest must be linear in lane order.
__device__ __forceinline__ void gload16(const void* g, void* l){
  __builtin_amdgcn_global_load_lds(
      (const __attribute__((address_space(1))) u32*)g,
      (__attribute__((address_space(3))) u32*)l, 16, 0, 0);
}

// ---------------------------------------------------------------------------
// fp32 -> bf16 trunc convert (memory-bound pre-pass for x). Exact-size grid.
// ---------------------------------------------------------------------------
__global__ __launch_bounds__(256)
void to_bf16(const float* __restrict__ s, u16* __restrict__ d)
{
  const size_t i = ((size_t)blockIdx.x * 256 + threadIdx.x) * 8;
  *(uint4*)(d + i) = pk8(s + i);
}

// ---------------------------------------------------------------------------
// Merged QKV GEMM. A (x, bf16) staged via global_load_lds; W (fp32) pk8.
// 128x128 tile, BK=32, 256 thr = 4 waves in 2x2, each wave 64x64 = 4x4 MFMA.
// which = blockIdx.x>>3: 0=Q (MODE1, scaled), 1=K (MODE1), 2=V (MODE2, V^T).
//   MODE1: mfma(W,A) -> lane=m, regs=n  -> uint2 stores in [bh][s][dk].
//   MODE2: mfma(A,W) -> lane=n(dd), regs=m(s) -> uint2 stores in [bh][dk][s].
// ---------------------------------------------------------------------------
__global__ __launch_bounds__(256, 3)
void gemm_qkv(const u16* __restrict__ A,
              const float* __restrict__ Wq, const float* __restrict__ bq_,
              const float* __restrict__ Wk, const float* __restrict__ bk_,
              const float* __restrict__ Wv, const float* __restrict__ bv_,
              u16* __restrict__ Qo, u16* __restrict__ Ko, u16* __restrict__ Vo)
{
  __shared__ __align__(16) u16 As[128*32];
  __shared__ __align__(16) u16 Bs[128*32];

  const int t     = threadIdx.x;
  const int which = (int)blockIdx.x >> 3;
  const int n0    = ((int)blockIdx.x & 7) * 128;
  const int m0    = (int)blockIdx.y * 128;
  const float* W    = which==0 ? Wq  : which==1 ? Wk  : Wv;
  const float* bias = which==0 ? bq_ : which==1 ? bk_ : bv_;

  const int wid = t >> 6, lane = t & 63;
  const int wr  = wid >> 1, wc = wid & 1;
  const int quad = lane >> 4, l15 = lane & 15;
  // chunk c -> row = c>>2, koff = (c&3)*8 ; LDS layout [row][32], linear in c
  const int rA0 = t >> 2, kA0 = (t & 3) * 8;   // chunk c0 = t      (rows 0..63)
  const int rA1 = rA0 + 64;                    // chunk c1 = t+256  (rows 64..127)

  floatx4 acc[4][4] = {};

  for (int k0 = 0; k0 < D_MODEL; k0 += 32) {
    __syncthreads();
    gload16(A + (size_t)(m0 + rA0)*D_MODEL + k0 + kA0, (char*)As + t*16);
    gload16(A + (size_t)(m0 + rA1)*D_MODEL + k0 + kA0, (char*)As + 4096 + t*16);
    *(uint4*)&Bs[t*8]         = pk8(W + (size_t)(n0 + rA0)*D_MODEL + k0 + kA0);
    *(uint4*)&Bs[(t + 256)*8] = pk8(W + (size_t)(n0 + rA1)*D_MODEL + k0 + kA0);
    __syncthreads();   // compiler emits vmcnt(0)+lgkmcnt(0) drain here

    bf16x8 af[4], bf[4];
#pragma unroll
    for (int i = 0; i < 4; ++i) {
      af[i] = *(const bf16x8*)&As[(wr*64 + i*16 + l15)*32 + quad*8];
      bf[i] = *(const bf16x8*)&Bs[(wc*64 + i*16 + l15)*32 + quad*8];
    }
    if (which == 2) {
#pragma unroll
      for (int mi = 0; mi < 4; ++mi)
#pragma unroll
        for (int nj = 0; nj < 4; ++nj)
          acc[mi][nj] = __builtin_amdgcn_mfma_f32_16x16x32_bf16(af[mi], bf[nj], acc[mi][nj], 0, 0, 0);
    } else {
#pragma unroll
      for (int mi = 0; mi < 4; ++mi)
#pragma unroll
        for (int nj = 0; nj < 4; ++nj)
          acc[mi][nj] = __builtin_amdgcn_mfma_f32_16x16x32_bf16(bf[nj], af[mi], acc[mi][nj], 0, 0, 0);
    }
  }

  if (which != 2) {
    // lane = m, regs = n-consecutive
    const float scale = which==0 ? 0.18033688f : 1.0f;  // 1/sqrt(dk)*log2(e) for Q
    u16* out = which==0 ? Qo : Ko;
#pragma unroll
    for (int nj = 0; nj < 4; ++nj) {
      const int nb = n0 + wc*64 + nj*16 + quad*4;
      const float4 b4 = *(const float4*)(bias + nb);
#pragma unroll
      for (int mi = 0; mi < 4; ++mi) {
        const int m = m0 + wr*64 + mi*16 + l15;
        floatx4 d = acc[mi][nj];
        const float v0 = (d[0]+b4.x)*scale, v1 = (d[1]+b4.y)*scale;
        const float v2 = (d[2]+b4.z)*scale, v3 = (d[3]+b4.w)*scale;
        const int b = m >> 11, s = m & 2047, h = nb >> 6, dd = nb & 63;
        u16* dst = out + ((((size_t)b*NHEAD + h)*SEQ + s) << 6) + dd;
        *(uint2*)dst = make_uint2(pkh(v0, v1), pkh(v2, v3));
      }
    }
  } else {
    // lane = n (dd), regs = m (s)-consecutive
#pragma unroll
    for (int nj = 0; nj < 4; ++nj) {
      const int n  = n0 + wc*64 + nj*16 + l15;
      const float bvv = bias[n];
      const int h = n >> 6, dd = n & 63;
#pragma unroll
      for (int mi = 0; mi < 4; ++mi) {
        const int mb = m0 + wr*64 + mi*16 + quad*4;
        const int b = mb >> 11, s = mb & 2047;
        floatx4 d = acc[mi][nj];
        u16* dst = Vo + (((size_t)b*NHEAD + h)*DK + dd)*SEQ + s;
        *(uint2*)dst = make_uint2(pkh(d[0]+bvv, d[1]+bvv), pkh(d[2]+bvv, d[3]+bvv));
      }
    }
  }
}

// ---------------------------------------------------------------------------
// Output projection: A = O (bf16) via global_load_lds, W = Wo fp32 pk8,
// fp32 [m][N] epilogue (MODE0).
// ---------------------------------------------------------------------------
__global__ __launch_bounds__(256, 3)
void gemm_out(const u16* __restrict__ A, const float* __restrict__ W,
              const float* __restrict__ bias, float* __restrict__ out)
{
  __shared__ __align__(16) u16 As[128*32];
  __shared__ __align__(16) u16 Bs[128*32];

  const int t  = threadIdx.x;
  const int n0 = (int)blockIdx.x * 128;
  const int m0 = (int)blockIdx.y * 128;
  const int wid = t >> 6, lane = t & 63;
  const int wr  = wid >> 1, wc = wid & 1;
  const int quad = lane >> 4, l15 = lane & 15;
  const int rA0 = t >> 2, kA0 = (t & 3) * 8;
  const int rA1 = rA0 + 64;

  floatx4 acc[4][4] = {};

  for (int k0 = 0; k0 < D_MODEL; k0 += 32) {
    __syncthreads();
    gload16(A + (size_t)(m0 + rA0)*D_MODEL + k0 + kA0, (char*)As + t*16);
    gload16(A + (size_t)(m0 + rA1)*D_MODEL + k0 + kA0, (char*)As + 4096 + t*16);
    *(uint4*)&Bs[t*8]         = pk8(W + (size_t)(n0 + rA0)*D_MODEL + k0 + kA0);
    *(uint4*)&Bs[(t + 256)*8] = pk8(W + (size_t)(n0 + rA1)*D_MODEL + k0 + kA0);
    __syncthreads();

    bf16x8 af[4], bf[4];
#pragma unroll
    for (int i = 0; i < 4; ++i) {
      af[i] = *(const bf16x8*)&As[(wr*64 + i*16 + l15)*32 + quad*8];
      bf[i] = *(const bf16x8*)&Bs[(wc*64 + i*16 + l15)*32 + quad*8];
    }
#pragma unroll
    for (int mi = 0; mi < 4; ++mi)
#pragma unroll
      for (int nj = 0; nj < 4; ++nj)
        acc[mi][nj] = __builtin_amdgcn_mfma_f32_16x16x32_bf16(bf[nj], af[mi], acc[mi][nj], 0, 0, 0);
  }

#pragma unroll
  for (int nj = 0; nj < 4; ++nj) {
    const int nb = n0 + wc*64 + nj*16 + quad*4;
    const float4 b4 = *(const float4*)(bias + nb);
#pragma unroll
    for (int mi = 0; mi < 4; ++mi) {
      const int m = m0 + wr*64 + mi*16 + l15;
      floatx4 d = acc[mi][nj];
      float4 s4 = make_float4(d[0]+b4.x, d[1]+b4.y, d[2]+b4.z, d[3]+b4.w);
      *(float4*)(out + (size_t)m*D_MODEL + nb) = s4;
    }
  }
}

// ---------------------------------------------------------------------------
// MFMA flash attention. Grid (16, B*H), 256 thr = 4 waves, 16 queries/wave.
// Balanced pairing: block pid handles query-blocks {31-pid, pid} -> every
// block runs exactly 33 K-tile iterations (uniform makespan, 4 blocks/CU).
//  phase 1: S^T = K·Q^T (16x16x32 f16); C: col=query=lane&15, row=key.
//  softmax: per-query stats; l kept per-lane-partial, reduced in epilogue.
//  phase 2: O^T = V^T·P^T (16x16x16 f16); P^T B-frag == S^T C-layout.
// Wave-uniform ktmax skips fully-masked 16-key subtiles on the diagonal.
// ---------------------------------------------------------------------------
__global__ __launch_bounds__(256, 6)
void attn_fwd(const _Float16* __restrict__ Q, const _Float16* __restrict__ K,
              const _Float16* __restrict__ Vt, u16* __restrict__ O)
{
  __shared__ __align__(16) _Float16 Ks[64][72];
  __shared__ __align__(16) _Float16 Vs[64][72];

  const int bh   = blockIdx.y;
  const int pid  = blockIdx.x;              // 0..15
  const int t    = threadIdx.x;
  const int w    = t >> 6, lane = t & 63;
  const int quad = lane >> 4, l15 = lane & 15;
  const int sr = t >> 3, sc8 = (t & 7) * 8;
  const _Float16* Kb = K  + (size_t)bh * SEQ * DK;
  const _Float16* Vb = Vt + (size_t)bh * DK * SEQ;

#pragma unroll 1
  for (int item = 0; item < 2; ++item) {
    const int rblk = item ? pid : (SEQ/64 - 1 - pid);   // heavy half first
    const int r0   = rblk * 64;
    const int qb   = r0 + w * 16;
    const int query = qb + l15;

    half8_t qf[2];
    {
      const _Float16* Qp = Q + ((size_t)bh * SEQ + query) * DK + quad * 8;
      qf[0] = *(const half8_t*)(Qp);
      qf[1] = *(const half8_t*)(Qp + 32);
    }

    float mrow = -1e30f, lpart = 0.f;
    floatx4 o[4] = {};

    const int jend = r0 + 64;
    for (int j0 = 0; j0 < jend; j0 += 64) {
      __syncthreads();
      *(uint4*)&Ks[sr     ][sc8] = *(const uint4*)(Kb + (size_t)(j0 + sr     )*DK + sc8);
      *(uint4*)&Ks[sr + 32][sc8] = *(const uint4*)(Kb + (size_t)(j0 + sr + 32)*DK + sc8);
      *(uint4*)&Vs[sr     ][sc8] = *(const uint4*)(Vb + (size_t)(sr     )*SEQ + j0 + sc8);
      *(uint4*)&Vs[sr + 32][sc8] = *(const uint4*)(Vb + (size_t)(sr + 32)*SEQ + j0 + sc8);
      __syncthreads();
      if (j0 > qb + 15) continue;                      // fully masked for wave
      const int ktmax = ((qb + 15 - j0) >> 4) + 1;     // 1..4, wave-uniform

      // ---- phase 1
      floatx4 st[4];
#pragma unroll
      for (int kt = 0; kt < 4; ++kt) {
        if (kt < ktmax) {
          half8_t a0 = *(const half8_t*)&Ks[kt*16 + l15][quad*8];
          half8_t a1 = *(const half8_t*)&Ks[kt*16 + l15][32 + quad*8];
          floatx4 s = {};
          s = __builtin_amdgcn_mfma_f32_16x16x32_f16(a0, qf[0], s, 0, 0, 0);
          s = __builtin_amdgcn_mfma_f32_16x16x32_f16(a1, qf[1], s, 0, 0, 0);
          st[kt] = s;
        }
      }
      // ---- causal mask (only subtiles straddling the diagonal)
#pragma unroll
      for (int kt = 0; kt < 4; ++kt) {
        if (kt < ktmax && j0 + kt*16 + 15 > qb) {
#pragma unroll
          for (int r = 0; r < 4; ++r)
            if (j0 + kt*16 + quad*4 + r > query) st[kt][r] = -1e30f;
        }
      }
      // ---- online softmax (log2 domain; Q pre-scaled by 0.125*log2e)
      float m0 = -1e30f;
#pragma unroll
      for (int kt = 0; kt < 4; ++kt)
        if (kt < ktmax)
          m0 = fmaxf(m0, fmaxf(fmaxf(st[kt][0], st[kt][1]), fmaxf(st[kt][2], st[kt][3])));
      m0 = fmaxf(m0, __shfl_xor(m0, 16));
      m0 = fmaxf(m0, __shfl_xor(m0, 32));
      const float mn    = fmaxf(mrow, m0);
      const float alpha = exp2f(mrow - mn);            // 0 on first live tile
      mrow = mn;
      lpart *= alpha;
      half4_t pf[4];
#pragma unroll
      for (int kt = 0; kt < 4; ++kt) {
        if (kt < ktmax) {
          const float p0 = exp2f(st[kt][0] - mn), p1 = exp2f(st[kt][1] - mn);
          const float p2 = exp2f(st[kt][2] - mn), p3 = exp2f(st[kt][3] - mn);
          lpart += (p0 + p1) + (p2 + p3);
          union { half4_t h; uint2 u; } pc;
          pc.u = make_uint2(pkh(p0, p1), pkh(p2, p3));
          pf[kt] = pc.h;
        }
      }
#pragma unroll
      for (int dt = 0; dt < 4; ++dt) {
        o[dt][0] *= alpha; o[dt][1] *= alpha; o[dt][2] *= alpha; o[dt][3] *= alpha;
      }
      // ---- phase 2
#pragma unroll
      for (int dt = 0; dt < 4; ++dt)
#pragma unroll
        for (int kt = 0; kt < 4; ++kt) {
          if (kt < ktmax) {
            half4_t vf = *(const half4_t*)&Vs[dt*16 + l15][kt*16 + quad*4];
            o[dt] = __builtin_amdgcn_mfma_f32_16x16x16f16(vf, pf[kt], o[dt], 0, 0, 0);
          }
        }
    }

    // ---- epilogue: deferred l reduction, O bf16 [B,S,D]
    float l = lpart;
    l += __shfl_xor(l, 16);
    l += __shfl_xor(l, 32);
    const float inv = 1.0f / l;
    const int b = bh >> 4, h = bh & 15;
    u16* Op = O + ((size_t)(b * SEQ + query)) * D_MODEL + h * DK + quad * 4;
#pragma unroll
    for (int dt = 0; dt < 4; ++dt) {
      u32 lo = ((u32)f2bf(o[dt][1] * inv) << 16) | f2bf(o[dt][0] * inv);
      u32 hi = ((u32)f2bf(o[dt][3] * inv) << 16) | f2bf(o[dt][2] * inv);
      *(uint2*)(Op + dt * 16) = make_uint2(lo, hi);
    }
  }
}

// ---------------------------------------------------------------------------
extern "C" void kernel_launch(void* const* d_in, const int* in_sizes, int n_in,
                              void* d_out, int out_size, void* d_ws, size_t ws_size,
                              hipStream_t stream)
{
  const float* x  = (const float*)d_in[0];
  const float* Wq = (const float*)d_in[1];
  const float* bq = (const float*)d_in[2];
  const float* Wk = (const float*)d_in[3];
  const float* bk = (const float*)d_in[4];
  const float* Wv = (const float*)d_in[5];
  const float* bv = (const float*)d_in[6];
  const float* Wo = (const float*)d_in[7];
  const float* bo = (const float*)d_in[8];

  const size_t tsz = (size_t)MTOT * D_MODEL;
  u16* Qw  = (u16*)d_ws;
  u16* Kw  = Qw + tsz;
  u16* Vtw = Kw + tsz;
  u16* S3  = Vtw + tsz;      // shared slot: xb (pre-attn) then O (post-attn)

  // x -> bf16 (trunc, same rounding as the old in-GEMM pk8 path)
  to_bf16<<<(MTOT*D_MODEL)/(256*8), 256, 0, stream>>>(x, S3);

  // merged QKV: which = blockIdx.x>>3
  gemm_qkv<<<dim3(24, MTOT/128), 256, 0, stream>>>(
      S3, Wq, bq, Wk, bk, Wv, bv, Qw, Kw, Vtw);

  attn_fwd<<<dim3(SEQ/128, BATCH*NHEAD), 256, 0, stream>>>(
      (const _Float16*)Qw, (const _Float16*)Kw, (const _Float16*)Vtw, S3);

  gemm_out<<<dim3(D_MODEL/128, MTOT/128), 256, 0, stream>>>(
      S3, Wo, bo, (float*)d_out);
}

// Round 6
// 472.142 us; speedup vs baseline: 1.0080x; 1.0080x over previous
//
#include <hip/hip_runtime.h>
#include <stdint.h>

// CausalMultiHeadAttention — round 7 (resubmit; round-5 bench was an infra
// GPUAcquisitionTimeout, no counters produced).
// r6 post-mortem: gemm_qkv was HBM-WRITE-bound (WRITE_SIZE ~300 MB vs 48 MB
// ideal = 6x amplification from 8 B/lane scattered fp16 stores; partial-line
// evictions under L2 thrash). Fix:
//  - LDS-staged coalesced epilogues (gemm_qkv + gemm_out): each wave stages
//    its C-subtile into its 4 KB slice of the (reused) As/Bs LDS, XOR-swizzled
//    against bank conflicts, then stores 16 B/lane wave-contiguous rows —
//    every 64 B line written by exactly one instruction.
//  - 'which' moved to slow grid axis (grid 8x192): Q/K/V phases sequential,
//    one W matrix live at a time; A bf16 (16 MB) L3-resident across phases.
//  - attn (balanced pairing), to_bf16, staging via global_load_lds unchanged.
// ws: Q | K | Vt (fp16) | {xb then O} (bf16) = 67.1 MB (proven size).

#define D_MODEL 1024
#define NHEAD   16
#define DK      64
#define BATCH   4
#define SEQ     2048
#define MTOT    (BATCH*SEQ)   // 8192

typedef unsigned short u16;
typedef unsigned int   u32;
typedef __bf16    bf16x8  __attribute__((ext_vector_type(8)));
typedef float     floatx4 __attribute__((ext_vector_type(4)));
typedef __fp16    fp16x2  __attribute__((ext_vector_type(2)));
typedef _Float16  half4_t __attribute__((ext_vector_type(4)));
typedef _Float16  half8_t __attribute__((ext_vector_type(8)));

// round-to-nearest-even f32 -> bf16 (epilogue only)
__device__ __forceinline__ u16 f2bf(float f){
  union { float f; u32 u; } c; c.f = f;
  u32 x = c.u;
  x += 0x7fffu + ((x >> 16) & 1u);
  return (u16)(x >> 16);
}
// f32 pair -> packed fp16 bits (RTZ, hardware packed cvt)
__device__ __forceinline__ u32 pkh(float a, float b){
  union { fp16x2 h; u32 u; } c; c.h = __builtin_amdgcn_cvt_pkrtz(a, b); return c.u;
}
// 8 fp32 -> 8 bf16 by truncation: one v_perm per pair
__device__ __forceinline__ uint4 pk8(const float* __restrict__ p){
  uint4 a = *(const uint4*)p;
  uint4 b = *(const uint4*)(p + 4);
  uint4 r;
  r.x = __builtin_amdgcn_perm(a.y, a.x, 0x07060302);
  r.y = __builtin_amdgcn_perm(a.w, a.z, 0x07060302);
  r.z = __builtin_amdgcn_perm(b.y, b.x, 0x07060302);
  r.w = __builtin_amdgcn_perm(b.w, b.z, 0x07060302);
  return r;
}
// async global->LDS, 16B per lane. LDS dest must be linear in lane order.
__device__ __forceinline__ void gload16(const void* g, void* l){
  __builtin_amdgcn_global_load_lds(
      (const __attribute__((address_space(1))) u32*)g,
      (__attribute__((address_space(3))) u32*)l, 16, 0, 0);
}

// ---------------------------------------------------------------------------
// fp32 -> bf16 trunc convert (memory-bound pre-pass for x). Exact-size grid.
// ---------------------------------------------------------------------------
__global__ __launch_bounds__(256)
void to_bf16(const float* __restrict__ s, u16* __restrict__ d)
{
  const size_t i = ((size_t)blockIdx.x * 256 + threadIdx.x) * 8;
  *(uint4*)(d + i) = pk8(s + i);
}

// ---------------------------------------------------------------------------
// Merged QKV GEMM. A (x, bf16) staged via global_load_lds; W (fp32) pk8.
// 128x128 tile, BK=32, 256 thr = 4 waves in 2x2, each wave 64x64 = 4x4 MFMA.
// Grid (8, 192): which = y>>6 (slow axis: Q then K then V), m0=(y&63)*128,
// n0 = x*128.
//   MODE1 (Q,K): mfma(W,A) -> lane=m, regs=n. Epilogue LDS-staged to
//     [bh][s][dk]: 16 B/lane, 8 rows x 128 B contiguous per store instr.
//   MODE2 (V):   mfma(A,W) -> lane=n(dd), regs=m(s). LDS-staged to
//     [bh][dk][s]: same coalescing with (dd,s) roles swapped.
// ---------------------------------------------------------------------------
__global__ __launch_bounds__(256, 3)
void gemm_qkv(const u16* __restrict__ A,
              const float* __restrict__ Wq, const float* __restrict__ bq_,
              const float* __restrict__ Wk, const float* __restrict__ bk_,
              const float* __restrict__ Wv, const float* __restrict__ bv_,
              u16* __restrict__ Qo, u16* __restrict__ Ko, u16* __restrict__ Vo)
{
  __shared__ __align__(16) u16 smem[8192];      // 16 KB: As = [0,8K), Bs = [8K,16K)
  u16* Bsp = smem + 4096;

  const int t     = threadIdx.x;
  const int which = (int)blockIdx.y >> 6;
  const int m0    = ((int)blockIdx.y & 63) * 128;
  const int n0    = (int)blockIdx.x * 128;
  const float* W    = which==0 ? Wq  : which==1 ? Wk  : Wv;
  const float* bias = which==0 ? bq_ : which==1 ? bk_ : bv_;

  const int wid = t >> 6, lane = t & 63;
  const int wr  = wid >> 1, wc = wid & 1;
  const int quad = lane >> 4, l15 = lane & 15;
  const int rA0 = t >> 2, kA0 = (t & 3) * 8;   // chunk c0 = t (rows 0..63)
  const int rA1 = rA0 + 64;                    // chunk c1 = t+256 (rows 64..127)

  floatx4 acc[4][4] = {};

  for (int k0 = 0; k0 < D_MODEL; k0 += 32) {
    __syncthreads();
    gload16(A + (size_t)(m0 + rA0)*D_MODEL + k0 + kA0, (char*)smem + t*16);
    gload16(A + (size_t)(m0 + rA1)*D_MODEL + k0 + kA0, (char*)smem + 4096 + t*16);
    *(uint4*)&Bsp[t*8]         = pk8(W + (size_t)(n0 + rA0)*D_MODEL + k0 + kA0);
    *(uint4*)&Bsp[(t + 256)*8] = pk8(W + (size_t)(n0 + rA1)*D_MODEL + k0 + kA0);
    __syncthreads();

    bf16x8 af[4], bf[4];
#pragma unroll
    for (int i = 0; i < 4; ++i) {
      af[i] = *(const bf16x8*)&smem[(wr*64 + i*16 + l15)*32 + quad*8];
      bf[i] = *(const bf16x8*)&Bsp[(wc*64 + i*16 + l15)*32 + quad*8];
    }
    if (which == 2) {
#pragma unroll
      for (int mi = 0; mi < 4; ++mi)
#pragma unroll
        for (int nj = 0; nj < 4; ++nj)
          acc[mi][nj] = __builtin_amdgcn_mfma_f32_16x16x32_bf16(af[mi], bf[nj], acc[mi][nj], 0, 0, 0);
    } else {
#pragma unroll
      for (int mi = 0; mi < 4; ++mi)
#pragma unroll
        for (int nj = 0; nj < 4; ++nj)
          acc[mi][nj] = __builtin_amdgcn_mfma_f32_16x16x32_bf16(bf[nj], af[mi], acc[mi][nj], 0, 0, 0);
    }
  }

  // ---- LDS-staged coalesced epilogue. Per-wave 4 KB slice; 2 passes.
  __syncthreads();                              // all waves done with As/Bs
  char* st = (char*)smem + wid*4096;
  const int hq    = (n0 + wc*64) >> 6;          // head (wave n-range = 1 head)
  const int mbase = m0 + wr*64;
  const int bb    = mbase >> 11;                // batch (const per wave)
  const int sb    = mbase & 2047;

  if (which != 2) {
    // lane=m(s), regs=n(dd). Stage [32 s-rows][128 B dd], swizzled.
    const float scale = which==0 ? 0.18033688f : 1.0f;  // 1/sqrt(dk)*log2(e)
    u16* out = which==0 ? Qo : Ko;
#pragma unroll
    for (int p = 0; p < 2; ++p) {
#pragma unroll
      for (int mi2 = 0; mi2 < 2; ++mi2) {
        const int mi  = p*2 + mi2;
        const int row = mi2*16 + l15;
        const u32 sw  = (u32)((row & 7) << 4);
#pragma unroll
        for (int nj = 0; nj < 4; ++nj) {
          const float4 b4 = *(const float4*)(bias + n0 + wc*64 + nj*16 + quad*4);
          floatx4 d = acc[mi][nj];
          const u32 lo = pkh((d[0]+b4.x)*scale, (d[1]+b4.y)*scale);
          const u32 hi = pkh((d[2]+b4.z)*scale, (d[3]+b4.w)*scale);
          const u32 byte = (u32)row*128 + (((u32)(nj*32 + quad*8)) ^ sw);
          *(uint2*)(st + byte) = make_uint2(lo, hi);
        }
      }
      asm volatile("s_waitcnt lgkmcnt(0)" ::: "memory");
#pragma unroll
      for (int i = 0; i < 4; ++i) {
        const int row   = i*8 + (lane >> 3);
        const u32 byte  = (u32)row*128 + (((u32)(lane & 7) * 16) ^ (u32)((row & 7) << 4));
        const uint4 v   = *(const uint4*)(st + byte);
        const int s     = sb + p*32 + row;
        const int dd    = (lane & 7) * 8;
        *(uint4*)(out + ((((size_t)bb*NHEAD + hq)*SEQ + s) << 6) + dd) = v;
      }
      asm volatile("s_waitcnt lgkmcnt(0)" ::: "memory");
    }
  } else {
    // lane=n(dd), regs=m(s). Stage [32 dd-rows][128 B s], swizzled.
#pragma unroll
    for (int p = 0; p < 2; ++p) {
#pragma unroll
      for (int nj2 = 0; nj2 < 2; ++nj2) {
        const int nj  = p*2 + nj2;
        const int row = nj2*16 + l15;
        const u32 sw  = (u32)((row & 7) << 4);
        const float bvv = bias[n0 + wc*64 + nj*16 + l15];
#pragma unroll
        for (int mi = 0; mi < 4; ++mi) {
          floatx4 d = acc[mi][nj];
          const u32 lo = pkh(d[0]+bvv, d[1]+bvv);
          const u32 hi = pkh(d[2]+bvv, d[3]+bvv);
          const u32 byte = (u32)row*128 + (((u32)(mi*32 + quad*8)) ^ sw);
          *(uint2*)(st + byte) = make_uint2(lo, hi);
        }
      }
      asm volatile("s_waitcnt lgkmcnt(0)" ::: "memory");
#pragma unroll
      for (int i = 0; i < 4; ++i) {
        const int row   = i*8 + (lane >> 3);
        const u32 byte  = (u32)row*128 + (((u32)(lane & 7) * 16) ^ (u32)((row & 7) << 4));
        const uint4 v   = *(const uint4*)(st + byte);
        const int dd    = p*32 + row;
        const int s     = sb + (lane & 7) * 8;
        *(uint4*)(Vo + (((size_t)bb*NHEAD + hq)*DK + dd)*SEQ + s) = v;
      }
      asm volatile("s_waitcnt lgkmcnt(0)" ::: "memory");
    }
  }
}

// ---------------------------------------------------------------------------
// Output projection: A = O (bf16) via global_load_lds, W = Wo fp32 pk8,
// fp32 [m][1024] out. LDS-staged epilogue: 4 passes of [16 m][256 B n],
// stores 16 B/lane, 4 rows x 256 B contiguous per instr.
// ---------------------------------------------------------------------------
__global__ __launch_bounds__(256, 3)
void gemm_out(const u16* __restrict__ A, const float* __restrict__ W,
              const float* __restrict__ bias, float* __restrict__ outp)
{
  __shared__ __align__(16) u16 smem[8192];
  u16* Bsp = smem + 4096;

  const int t  = threadIdx.x;
  const int n0 = (int)blockIdx.x * 128;
  const int m0 = (int)blockIdx.y * 128;
  const int wid = t >> 6, lane = t & 63;
  const int wr  = wid >> 1, wc = wid & 1;
  const int quad = lane >> 4, l15 = lane & 15;
  const int rA0 = t >> 2, kA0 = (t & 3) * 8;
  const int rA1 = rA0 + 64;

  floatx4 acc[4][4] = {};

  for (int k0 = 0; k0 < D_MODEL; k0 += 32) {
    __syncthreads();
    gload16(A + (size_t)(m0 + rA0)*D_MODEL + k0 + kA0, (char*)smem + t*16);
    gload16(A + (size_t)(m0 + rA1)*D_MODEL + k0 + kA0, (char*)smem + 4096 + t*16);
    *(uint4*)&Bsp[t*8]         = pk8(W + (size_t)(n0 + rA0)*D_MODEL + k0 + kA0);
    *(uint4*)&Bsp[(t + 256)*8] = pk8(W + (size_t)(n0 + rA1)*D_MODEL + k0 + kA0);
    __syncthreads();

    bf16x8 af[4], bf[4];
#pragma unroll
    for (int i = 0; i < 4; ++i) {
      af[i] = *(const bf16x8*)&smem[(wr*64 + i*16 + l15)*32 + quad*8];
      bf[i] = *(const bf16x8*)&Bsp[(wc*64 + i*16 + l15)*32 + quad*8];
    }
#pragma unroll
    for (int mi = 0; mi < 4; ++mi)
#pragma unroll
      for (int nj = 0; nj < 4; ++nj)
        acc[mi][nj] = __builtin_amdgcn_mfma_f32_16x16x32_bf16(bf[nj], af[mi], acc[mi][nj], 0, 0, 0);
  }

  // ---- LDS-staged epilogue: 4 passes (p = mi), [16 rows][256 B].
  __syncthreads();
  char* st = (char*)smem + wid*4096;
  const int nbase = n0 + wc*64;
  const int mbase = m0 + wr*64;
#pragma unroll
  for (int p = 0; p < 4; ++p) {
    const int row = l15;
    const u32 sw  = (u32)((row & 7) << 4);
#pragma unroll
    for (int nj = 0; nj < 4; ++nj) {
      const float4 b4 = *(const float4*)(bias + nbase + nj*16 + quad*4);
      floatx4 d = acc[p][nj];
      const float4 v = make_float4(d[0]+b4.x, d[1]+b4.y, d[2]+b4.z, d[3]+b4.w);
      const u32 byte = (u32)row*256 + (((u32)(nj*64 + quad*16)) ^ sw);
      *(float4*)(st + byte) = v;
    }
    asm volatile("s_waitcnt lgkmcnt(0)" ::: "memory");
#pragma unroll
    for (int i = 0; i < 4; ++i) {
      const int row2 = i*4 + (lane >> 4);
      const u32 byte = (u32)row2*256 + (((u32)(lane & 15) * 16) ^ (u32)((row2 & 7) << 4));
      const float4 v = *(const float4*)(st + byte);
      const int m = mbase + p*16 + row2;
      const int n = nbase + (lane & 15) * 4;
      *(float4*)(outp + (size_t)m*D_MODEL + n) = v;
    }
    asm volatile("s_waitcnt lgkmcnt(0)" ::: "memory");
  }
}

// ---------------------------------------------------------------------------
// MFMA flash attention. Grid (16, B*H), 256 thr = 4 waves, 16 queries/wave.
// Balanced pairing: block pid handles query-blocks {31-pid, pid} -> every
// block runs exactly 33 K-tile iterations (uniform makespan, 4 blocks/CU).
//  phase 1: S^T = K·Q^T (16x16x32 f16); C: col=query=lane&15, row=key.
//  softmax: per-query stats; l kept per-lane-partial, reduced in epilogue.
//  phase 2: O^T = V^T·P^T (16x16x16 f16); P^T B-frag == S^T C-layout.
// Wave-uniform ktmax skips fully-masked 16-key subtiles on the diagonal.
// ---------------------------------------------------------------------------
__global__ __launch_bounds__(256, 6)
void attn_fwd(const _Float16* __restrict__ Q, const _Float16* __restrict__ K,
              const _Float16* __restrict__ Vt, u16* __restrict__ O)
{
  __shared__ __align__(16) _Float16 Ks[64][72];
  __shared__ __align__(16) _Float16 Vs[64][72];

  const int bh   = blockIdx.y;
  const int pid  = blockIdx.x;              // 0..15
  const int t    = threadIdx.x;
  const int w    = t >> 6, lane = t & 63;
  const int quad = lane >> 4, l15 = lane & 15;
  const int sr = t >> 3, sc8 = (t & 7) * 8;
  const _Float16* Kb = K  + (size_t)bh * SEQ * DK;
  const _Float16* Vb = Vt + (size_t)bh * DK * SEQ;

#pragma unroll 1
  for (int item = 0; item < 2; ++item) {
    const int rblk = item ? pid : (SEQ/64 - 1 - pid);   // heavy half first
    const int r0   = rblk * 64;
    const int qb   = r0 + w * 16;
    const int query = qb + l15;

    half8_t qf[2];
    {
      const _Float16* Qp = Q + ((size_t)bh * SEQ + query) * DK + quad * 8;
      qf[0] = *(const half8_t*)(Qp);
      qf[1] = *(const half8_t*)(Qp + 32);
    }

    float mrow = -1e30f, lpart = 0.f;
    floatx4 o[4] = {};

    const int jend = r0 + 64;
    for (int j0 = 0; j0 < jend; j0 += 64) {
      __syncthreads();
      *(uint4*)&Ks[sr     ][sc8] = *(const uint4*)(Kb + (size_t)(j0 + sr     )*DK + sc8);
      *(uint4*)&Ks[sr + 32][sc8] = *(const uint4*)(Kb + (size_t)(j0 + sr + 32)*DK + sc8);
      *(uint4*)&Vs[sr     ][sc8] = *(const uint4*)(Vb + (size_t)(sr     )*SEQ + j0 + sc8);
      *(uint4*)&Vs[sr + 32][sc8] = *(const uint4*)(Vb + (size_t)(sr + 32)*SEQ + j0 + sc8);
      __syncthreads();
      if (j0 > qb + 15) continue;                      // fully masked for wave
      const int ktmax = ((qb + 15 - j0) >> 4) + 1;     // 1..4, wave-uniform

      // ---- phase 1
      floatx4 st[4];
#pragma unroll
      for (int kt = 0; kt < 4; ++kt) {
        if (kt < ktmax) {
          half8_t a0 = *(const half8_t*)&Ks[kt*16 + l15][quad*8];
          half8_t a1 = *(const half8_t*)&Ks[kt*16 + l15][32 + quad*8];
          floatx4 s = {};
          s = __builtin_amdgcn_mfma_f32_16x16x32_f16(a0, qf[0], s, 0, 0, 0);
          s = __builtin_amdgcn_mfma_f32_16x16x32_f16(a1, qf[1], s, 0, 0, 0);
          st[kt] = s;
        }
      }
      // ---- causal mask (only subtiles straddling the diagonal)
#pragma unroll
      for (int kt = 0; kt < 4; ++kt) {
        if (kt < ktmax && j0 + kt*16 + 15 > qb) {
#pragma unroll
          for (int r = 0; r < 4; ++r)
            if (j0 + kt*16 + quad*4 + r > query) st[kt][r] = -1e30f;
        }
      }
      // ---- online softmax (log2 domain; Q pre-scaled by 0.125*log2e)
      float m0 = -1e30f;
#pragma unroll
      for (int kt = 0; kt < 4; ++kt)
        if (kt < ktmax)
          m0 = fmaxf(m0, fmaxf(fmaxf(st[kt][0], st[kt][1]), fmaxf(st[kt][2], st[kt][3])));
      m0 = fmaxf(m0, __shfl_xor(m0, 16));
      m0 = fmaxf(m0, __shfl_xor(m0, 32));
      const float mn    = fmaxf(mrow, m0);
      const float alpha = exp2f(mrow - mn);            // 0 on first live tile
      mrow = mn;
      lpart *= alpha;
      half4_t pf[4];
#pragma unroll
      for (int kt = 0; kt < 4; ++kt) {
        if (kt < ktmax) {
          const float p0 = exp2f(st[kt][0] - mn), p1 = exp2f(st[kt][1] - mn);
          const float p2 = exp2f(st[kt][2] - mn), p3 = exp2f(st[kt][3] - mn);
          lpart += (p0 + p1) + (p2 + p3);
          union { half4_t h; uint2 u; } pc;
          pc.u = make_uint2(pkh(p0, p1), pkh(p2, p3));
          pf[kt] = pc.h;
        }
      }
#pragma unroll
      for (int dt = 0; dt < 4; ++dt) {
        o[dt][0] *= alpha; o[dt][1] *= alpha; o[dt][2] *= alpha; o[dt][3] *= alpha;
      }
      // ---- phase 2
#pragma unroll
      for (int dt = 0; dt < 4; ++dt)
#pragma unroll
        for (int kt = 0; kt < 4; ++kt) {
          if (kt < ktmax) {
            half4_t vf = *(const half4_t*)&Vs[dt*16 + l15][kt*16 + quad*4];
            o[dt] = __builtin_amdgcn_mfma_f32_16x16x16f16(vf, pf[kt], o[dt], 0, 0, 0);
          }
        }
    }

    // ---- epilogue: deferred l reduction, O bf16 [B,S,D]
    float l = lpart;
    l += __shfl_xor(l, 16);
    l += __shfl_xor(l, 32);
    const float inv = 1.0f / l;
    const int b = bh >> 4, h = bh & 15;
    u16* Op = O + ((size_t)(b * SEQ + query)) * D_MODEL + h * DK + quad * 4;
#pragma unroll
    for (int dt = 0; dt < 4; ++dt) {
      u32 lo = ((u32)f2bf(o[dt][1] * inv) << 16) | f2bf(o[dt][0] * inv);
      u32 hi = ((u32)f2bf(o[dt][3] * inv) << 16) | f2bf(o[dt][2] * inv);
      *(uint2*)(Op + dt * 16) = make_uint2(lo, hi);
    }
  }
}

// ---------------------------------------------------------------------------
extern "C" void kernel_launch(void* const* d_in, const int* in_sizes, int n_in,
                              void* d_out, int out_size, void* d_ws, size_t ws_size,
                              hipStream_t stream)
{
  const float* x  = (const float*)d_in[0];
  const float* Wq = (const float*)d_in[1];
  const float* bq = (const float*)d_in[2];
  const float* Wk = (const float*)d_in[3];
  const float* bk = (const float*)d_in[4];
  const float* Wv = (const float*)d_in[5];
  const float* bv = (const float*)d_in[6];
  const float* Wo = (const float*)d_in[7];
  const float* bo = (const float*)d_in[8];

  const size_t tsz = (size_t)MTOT * D_MODEL;
  u16* Qw  = (u16*)d_ws;
  u16* Kw  = Qw + tsz;
  u16* Vtw = Kw + tsz;
  u16* S3  = Vtw + tsz;      // shared slot: xb (pre-attn) then O (post-attn)

  // x -> bf16 (trunc, same rounding as the in-GEMM pk8 path)
  to_bf16<<<(MTOT*D_MODEL)/(256*8), 256, 0, stream>>>(x, S3);

  // merged QKV: which = blockIdx.y>>6 (sequential phases)
  gemm_qkv<<<dim3(8, 192), 256, 0, stream>>>(
      S3, Wq, bq, Wk, bk, Wv, bv, Qw, Kw, Vtw);

  attn_fwd<<<dim3(SEQ/128, BATCH*NHEAD), 256, 0, stream>>>(
      (const _Float16*)Qw, (const _Float16*)Kw, (const _Float16*)Vtw, S3);

  gemm_out<<<dim3(D_MODEL/128, MTOT/128), 256, 0, stream>>>(
      S3, Wo, bo, (float*)d_out);
}

// Round 8
// 365.227 us; speedup vs baseline: 1.3031x; 1.2927x over previous
//
#include <hip/hip_runtime.h>
#include <stdint.h>

// CausalMultiHeadAttention — round 8 (resubmit; round-7 bench was an infra
// GPUAcquisitionTimeout, no counters produced).
// r7 post-mortem: FETCH/WRITE track per-XCD L2<->fabric traffic (8 private
// L2s); gemm traffic was ~8x unique working set because round-robin block
// dispatch spreads A-tile sharers across XCDs. r6/r7 GEMM changes (merge,
// global_load_lds, staged epilogue) were orthogonal to that and regressed.
// This round:
//  - GEMMs reverted to the r5-proven structure (separate launches, pk8 both
//    operands, plain LDS staging, launch_bounds(256,2)).
//  - ONE change to GEMMs: grid transposed to (64 m-tiles, 8 n-tiles) so the
//    8 blocks sharing an A-tile get flat%8 == m%8 -> same XCD, co-resident:
//    A fetched once per tile per GEMM (32 MB instead of 128 MB).
//  - attn: keeps balanced pairing (rode along passing in r6/r7); grid
//    transposed to (64 bh, 16 pid) so each bh's 16 blocks colocate on one
//    XCD -> K/V stay L2-resident.
// ws: Q | K | Vt (fp16) | O (bf16) = 67.1 MB (proven size).

#define D_MODEL 1024
#define NHEAD   16
#define DK      64
#define BATCH   4
#define SEQ     2048
#define MTOT    (BATCH*SEQ)   // 8192

typedef unsigned short u16;
typedef unsigned int   u32;
typedef __bf16    bf16x8  __attribute__((ext_vector_type(8)));
typedef float     floatx4 __attribute__((ext_vector_type(4)));
typedef __fp16    fp16x2  __attribute__((ext_vector_type(2)));
typedef _Float16  half4_t __attribute__((ext_vector_type(4)));
typedef _Float16  half8_t __attribute__((ext_vector_type(8)));

// round-to-nearest-even f32 -> bf16 (epilogue only)
__device__ __forceinline__ u16 f2bf(float f){
  union { float f; u32 u; } c; c.f = f;
  u32 x = c.u;
  x += 0x7fffu + ((x >> 16) & 1u);
  return (u16)(x >> 16);
}
// f32 pair -> packed fp16 bits (RTZ, hardware packed cvt)
__device__ __forceinline__ u32 pkh(float a, float b){
  union { fp16x2 h; u32 u; } c; c.h = __builtin_amdgcn_cvt_pkrtz(a, b); return c.u;
}
// 8 fp32 -> 8 bf16 by truncation: one v_perm per pair (staging fast path)
__device__ __forceinline__ uint4 pk8(const float* __restrict__ p){
  uint4 a = *(const uint4*)p;
  uint4 b = *(const uint4*)(p + 4);
  uint4 r;
  r.x = __builtin_amdgcn_perm(a.y, a.x, 0x07060302);
  r.y = __builtin_amdgcn_perm(a.w, a.z, 0x07060302);
  r.z = __builtin_amdgcn_perm(b.y, b.x, 0x07060302);
  r.w = __builtin_amdgcn_perm(b.w, b.z, 0x07060302);
  return r;
}

// ---------------------------------------------------------------------------
// GEMM: C[m,n] = (sum_k A[m,k]*W[n,k] + bias[n]) * scale.  A: MxK row-major
// (fp32, or bf16 if ABF16).  W: NxK fp32 row-major (nn.Linear weight).
// 128x128 tile, BK=32, 256 thr = 4 waves in 2x2, each wave 64x64 = 4x4 MFMA.
// Grid (64 m-tiles, 8 n-tiles): m0 = blockIdx.x*128, n0 = blockIdx.y*128.
// flat id = x + 64y -> XCD = x%8: all 8 n-blocks of an A-tile colocate.
//   MODE 0 (fp32 [m][N], d_out) / MODE 1 (fp16 [bh][s][dk]): mfma(W,A) ->
//     lane=m, regs=n-consecutive -> float4 / uint2 stores.
//   MODE 2 (fp16 [bh][dk][s], V^T): mfma(A,W) -> lane=n(dd), regs=m(s)
//     -> uint2 stores contiguous in s.
// ---------------------------------------------------------------------------
template<int MODE, int ABF16>
__global__ __launch_bounds__(256, 2)
void gemm_bt(const void* __restrict__ Av, const float* __restrict__ W,
             const float* __restrict__ bias, void* __restrict__ outv,
             float scale)
{
  __shared__ __align__(16) u16 As[128*32];
  __shared__ __align__(16) u16 Bs[128*32];

  const int t    = threadIdx.x;
  const int m0   = blockIdx.x * 128;       // transposed: m on fast axis
  const int n0   = blockIdx.y * 128;
  const int wid  = t >> 6, lane = t & 63;
  const int wr   = wid >> 1, wc = wid & 1;
  const int quad = lane >> 4, l15 = lane & 15;

  // staging chunks: c -> row = c>>2, koff = (c&3)*8 ; LDS layout [row][32]
  const int c0 = t, c1 = t + 256;
  const int r0c = c0 >> 2, k0c = (c0 & 3) * 8;
  const int r1c = c1 >> 2, k1c = (c1 & 3) * 8;

  const float* Af = (const float*)Av;
  const u16*   Ab = (const u16*)Av;

  floatx4 acc[4][4] = {};

  for (int k0 = 0; k0 < D_MODEL; k0 += 32) {
    __syncthreads();
    if (ABF16) {
      *(uint4*)&As[c0*8] = *(const uint4*)(Ab + (size_t)(m0 + r0c)*D_MODEL + k0 + k0c);
      *(uint4*)&As[c1*8] = *(const uint4*)(Ab + (size_t)(m0 + r1c)*D_MODEL + k0 + k1c);
    } else {
      *(uint4*)&As[c0*8] = pk8(Af + (size_t)(m0 + r0c)*D_MODEL + k0 + k0c);
      *(uint4*)&As[c1*8] = pk8(Af + (size_t)(m0 + r1c)*D_MODEL + k0 + k1c);
    }
    *(uint4*)&Bs[c0*8] = pk8(W + (size_t)(n0 + r0c)*D_MODEL + k0 + k0c);
    *(uint4*)&Bs[c1*8] = pk8(W + (size_t)(n0 + r1c)*D_MODEL + k0 + k1c);
    __syncthreads();

    bf16x8 af[4], bf[4];
#pragma unroll
    for (int i = 0; i < 4; ++i) {
      af[i] = *(const bf16x8*)&As[(wr*64 + i*16 + l15)*32 + quad*8];
      bf[i] = *(const bf16x8*)&Bs[(wc*64 + i*16 + l15)*32 + quad*8];
    }
#pragma unroll
    for (int mi = 0; mi < 4; ++mi)
#pragma unroll
      for (int nj = 0; nj < 4; ++nj) {
        if (MODE == 2)
          acc[mi][nj] = __builtin_amdgcn_mfma_f32_16x16x32_bf16(af[mi], bf[nj], acc[mi][nj], 0, 0, 0);
        else
          acc[mi][nj] = __builtin_amdgcn_mfma_f32_16x16x32_bf16(bf[nj], af[mi], acc[mi][nj], 0, 0, 0);
      }
  }

  if (MODE != 2) {
    // lane = m, regs = n-consecutive
#pragma unroll
    for (int nj = 0; nj < 4; ++nj) {
      const int nb = n0 + wc*64 + nj*16 + quad*4;
      const float4 b4 = *(const float4*)(bias + nb);
#pragma unroll
      for (int mi = 0; mi < 4; ++mi) {
        const int m = m0 + wr*64 + mi*16 + l15;
        floatx4 d = acc[mi][nj];
        const float v0 = (d[0]+b4.x)*scale, v1 = (d[1]+b4.y)*scale;
        const float v2 = (d[2]+b4.z)*scale, v3 = (d[3]+b4.w)*scale;
        if (MODE == 0) {
          float4 s4 = make_float4(v0, v1, v2, v3);
          *(float4*)((float*)outv + (size_t)m*D_MODEL + nb) = s4;
        } else {
          const int b = m >> 11, s = m & 2047, h = nb >> 6, dd = nb & 63;
          u16* dst = (u16*)outv + ((((size_t)b*NHEAD + h)*SEQ + s) << 6) + dd;
          *(uint2*)dst = make_uint2(pkh(v0, v1), pkh(v2, v3));
        }
      }
    }
  } else {
    // lane = n (dd), regs = m (s)-consecutive
#pragma unroll
    for (int nj = 0; nj < 4; ++nj) {
      const int n  = n0 + wc*64 + nj*16 + l15;
      const float bvv = bias[n];
      const int h = n >> 6, dd = n & 63;
#pragma unroll
      for (int mi = 0; mi < 4; ++mi) {
        const int mb = m0 + wr*64 + mi*16 + quad*4;
        const int b = mb >> 11, s = mb & 2047;
        floatx4 d = acc[mi][nj];
        u16* dst = (u16*)outv + (((size_t)b*NHEAD + h)*DK + dd)*SEQ + s;
        *(uint2*)dst = make_uint2(pkh(d[0]+bvv, d[1]+bvv), pkh(d[2]+bvv, d[3]+bvv));
      }
    }
  }
}

// ---------------------------------------------------------------------------
// MFMA flash attention. Grid (64 bh, 16 pid), 256 thr = 4 waves, 16 q/wave.
// XCD locality: flat = bh + 64*pid -> XCD = bh%8; each bh's 16 blocks
// colocate, K/V (512 KB/bh) stay L2-resident.
// Balanced pairing: block pid handles query-blocks {31-pid, pid} -> every
// block runs exactly 33 K-tile iterations (uniform makespan).
//  phase 1: S^T = K·Q^T (16x16x32 f16); C: col=query=lane&15, row=key.
//  softmax: per-query stats; l kept per-lane-partial, reduced in epilogue.
//  phase 2: O^T = V^T·P^T (16x16x16 f16); P^T B-frag == S^T C-layout.
// Wave-uniform ktmax skips fully-masked 16-key subtiles on the diagonal.
// ---------------------------------------------------------------------------
__global__ __launch_bounds__(256, 6)
void attn_fwd(const _Float16* __restrict__ Q, const _Float16* __restrict__ K,
              const _Float16* __restrict__ Vt, u16* __restrict__ O)
{
  __shared__ __align__(16) _Float16 Ks[64][72];
  __shared__ __align__(16) _Float16 Vs[64][72];

  const int bh   = blockIdx.x;              // 0..63  (bh%8 = home XCD)
  const int pid  = blockIdx.y;              // 0..15
  const int t    = threadIdx.x;
  const int w    = t >> 6, lane = t & 63;
  const int quad = lane >> 4, l15 = lane & 15;
  const int sr = t >> 3, sc8 = (t & 7) * 8;
  const _Float16* Kb = K  + (size_t)bh * SEQ * DK;
  const _Float16* Vb = Vt + (size_t)bh * DK * SEQ;

#pragma unroll 1
  for (int item = 0; item < 2; ++item) {
    const int rblk = item ? pid : (SEQ/64 - 1 - pid);   // heavy half first
    const int r0   = rblk * 64;
    const int qb   = r0 + w * 16;
    const int query = qb + l15;

    half8_t qf[2];
    {
      const _Float16* Qp = Q + ((size_t)bh * SEQ + query) * DK + quad * 8;
      qf[0] = *(const half8_t*)(Qp);
      qf[1] = *(const half8_t*)(Qp + 32);
    }

    float mrow = -1e30f, lpart = 0.f;
    floatx4 o[4] = {};

    const int jend = r0 + 64;
    for (int j0 = 0; j0 < jend; j0 += 64) {
      __syncthreads();
      *(uint4*)&Ks[sr     ][sc8] = *(const uint4*)(Kb + (size_t)(j0 + sr     )*DK + sc8);
      *(uint4*)&Ks[sr + 32][sc8] = *(const uint4*)(Kb + (size_t)(j0 + sr + 32)*DK + sc8);
      *(uint4*)&Vs[sr     ][sc8] = *(const uint4*)(Vb + (size_t)(sr     )*SEQ + j0 + sc8);
      *(uint4*)&Vs[sr + 32][sc8] = *(const uint4*)(Vb + (size_t)(sr + 32)*SEQ + j0 + sc8);
      __syncthreads();
      if (j0 > qb + 15) continue;                      // fully masked for wave
      const int ktmax = ((qb + 15 - j0) >> 4) + 1;     // 1..4, wave-uniform

      // ---- phase 1
      floatx4 st[4];
#pragma unroll
      for (int kt = 0; kt < 4; ++kt) {
        if (kt < ktmax) {
          half8_t a0 = *(const half8_t*)&Ks[kt*16 + l15][quad*8];
          half8_t a1 = *(const half8_t*)&Ks[kt*16 + l15][32 + quad*8];
          floatx4 s = {};
          s = __builtin_amdgcn_mfma_f32_16x16x32_f16(a0, qf[0], s, 0, 0, 0);
          s = __builtin_amdgcn_mfma_f32_16x16x32_f16(a1, qf[1], s, 0, 0, 0);
          st[kt] = s;
        }
      }
      // ---- causal mask (only subtiles straddling the diagonal)
#pragma unroll
      for (int kt = 0; kt < 4; ++kt) {
        if (kt < ktmax && j0 + kt*16 + 15 > qb) {
#pragma unroll
          for (int r = 0; r < 4; ++r)
            if (j0 + kt*16 + quad*4 + r > query) st[kt][r] = -1e30f;
        }
      }
      // ---- online softmax (log2 domain; Q pre-scaled by 0.125*log2e)
      float m0 = -1e30f;
#pragma unroll
      for (int kt = 0; kt < 4; ++kt)
        if (kt < ktmax)
          m0 = fmaxf(m0, fmaxf(fmaxf(st[kt][0], st[kt][1]), fmaxf(st[kt][2], st[kt][3])));
      m0 = fmaxf(m0, __shfl_xor(m0, 16));
      m0 = fmaxf(m0, __shfl_xor(m0, 32));
      const float mn    = fmaxf(mrow, m0);
      const float alpha = exp2f(mrow - mn);            // 0 on first live tile
      mrow = mn;
      lpart *= alpha;
      half4_t pf[4];
#pragma unroll
      for (int kt = 0; kt < 4; ++kt) {
        if (kt < ktmax) {
          const float p0 = exp2f(st[kt][0] - mn), p1 = exp2f(st[kt][1] - mn);
          const float p2 = exp2f(st[kt][2] - mn), p3 = exp2f(st[kt][3] - mn);
          lpart += (p0 + p1) + (p2 + p3);
          union { half4_t h; uint2 u; } pc;
          pc.u = make_uint2(pkh(p0, p1), pkh(p2, p3));
          pf[kt] = pc.h;
        }
      }
#pragma unroll
      for (int dt = 0; dt < 4; ++dt) {
        o[dt][0] *= alpha; o[dt][1] *= alpha; o[dt][2] *= alpha; o[dt][3] *= alpha;
      }
      // ---- phase 2
#pragma unroll
      for (int dt = 0; dt < 4; ++dt)
#pragma unroll
        for (int kt = 0; kt < 4; ++kt) {
          if (kt < ktmax) {
            half4_t vf = *(const half4_t*)&Vs[dt*16 + l15][kt*16 + quad*4];
            o[dt] = __builtin_amdgcn_mfma_f32_16x16x16f16(vf, pf[kt], o[dt], 0, 0, 0);
          }
        }
    }

    // ---- epilogue: deferred l reduction, O bf16 [B,S,D]
    float l = lpart;
    l += __shfl_xor(l, 16);
    l += __shfl_xor(l, 32);
    const float inv = 1.0f / l;
    const int b = bh >> 4, h = bh & 15;
    u16* Op = O + ((size_t)(b * SEQ + query)) * D_MODEL + h * DK + quad * 4;
#pragma unroll
    for (int dt = 0; dt < 4; ++dt) {
      u32 lo = ((u32)f2bf(o[dt][1] * inv) << 16) | f2bf(o[dt][0] * inv);
      u32 hi = ((u32)f2bf(o[dt][3] * inv) << 16) | f2bf(o[dt][2] * inv);
      *(uint2*)(Op + dt * 16) = make_uint2(lo, hi);
    }
  }
}

// ---------------------------------------------------------------------------
extern "C" void kernel_launch(void* const* d_in, const int* in_sizes, int n_in,
                              void* d_out, int out_size, void* d_ws, size_t ws_size,
                              hipStream_t stream)
{
  const float* x  = (const float*)d_in[0];
  const float* Wq = (const float*)d_in[1];
  const float* bq = (const float*)d_in[2];
  const float* Wk = (const float*)d_in[3];
  const float* bk = (const float*)d_in[4];
  const float* Wv = (const float*)d_in[5];
  const float* bv = (const float*)d_in[6];
  const float* Wo = (const float*)d_in[7];
  const float* bo = (const float*)d_in[8];

  const size_t tsz = (size_t)MTOT * D_MODEL;
  u16* Qw  = (u16*)d_ws;
  u16* Kw  = Qw + tsz;
  u16* Vtw = Kw + tsz;
  u16* Ow  = Vtw + tsz;                        // 67.1 MB total

  dim3 gg(MTOT/128, D_MODEL/128);              // (64 m-tiles, 8 n-tiles)
  // Q scale = 1/sqrt(dk) * log2(e): softmax runs in log2 domain
  gemm_bt<1,0><<<gg, 256, 0, stream>>>(x, Wq, bq, Qw,  0.18033688f);
  gemm_bt<1,0><<<gg, 256, 0, stream>>>(x, Wk, bk, Kw,  1.0f);
  gemm_bt<2,0><<<gg, 256, 0, stream>>>(x, Wv, bv, Vtw, 1.0f);

  attn_fwd<<<dim3(BATCH*NHEAD, SEQ/128), 256, 0, stream>>>(
      (const _Float16*)Qw, (const _Float16*)Kw, (const _Float16*)Vtw, Ow);

  gemm_bt<0,1><<<gg, 256, 0, stream>>>(Ow, Wo, bo, d_out, 1.0f);
}